// Round 1
// baseline (2242.756 us; speedup 1.0000x reference)
//
#include <hip/hip_runtime.h>
#include <math.h>

#define BLK 256

// ---------------- CSR build: hist -> scan -> scatter ----------------
__global__ void zero_int(int* __restrict__ p, int n) {
    int i = blockIdx.x * BLK + threadIdx.x;
    if (i < n) p[i] = 0;
}

__global__ void hist_dst(const int* __restrict__ dst, int* __restrict__ cnt, int E_) {
    int e = blockIdx.x * BLK + threadIdx.x;
    if (e < E_) atomicAdd(&cnt[dst[e]], 1);
}

// per-block reduction of counts -> bsum[block]
__global__ void scan_block(const int* __restrict__ cnt, int* __restrict__ bsum, int n) {
    __shared__ int s[BLK];
    int i = blockIdx.x * BLK + threadIdx.x;
    int t = threadIdx.x;
    s[t] = (i < n) ? cnt[i] : 0;
    __syncthreads();
    for (int off = BLK / 2; off > 0; off >>= 1) {
        if (t < off) s[t] += s[t + off];
        __syncthreads();
    }
    if (t == 0) bsum[blockIdx.x] = s[0];
}

// single block: exclusive scan of bsum[0..nb) (nb <= 512)
__global__ void scan_bsums(int* __restrict__ bsum, int nb) {
    __shared__ int s[512];
    int t = threadIdx.x;
    int v = (t < nb) ? bsum[t] : 0;
    s[t] = v;
    __syncthreads();
    for (int off = 1; off < 512; off <<= 1) {
        int u = 0;
        if (t >= off) u = s[t - off];
        __syncthreads();
        if (t >= off) s[t] += u;
        __syncthreads();
    }
    if (t < nb) bsum[t] = s[t] - v;  // exclusive
}

// block-local exclusive scan + block offset; writes offs, resets cursor, computes dinv
__global__ void scan_final(int* cntcur, const int* __restrict__ bsum_ex,
                           int* __restrict__ offs, float* __restrict__ dinv,
                           int n, int E_) {
    __shared__ int s[BLK];
    int i = blockIdx.x * BLK + threadIdx.x;
    int t = threadIdx.x;
    int v = (i < n) ? cntcur[i] : 0;
    s[t] = v;
    __syncthreads();
    for (int off = 1; off < BLK; off <<= 1) {
        int u = 0;
        if (t >= off) u = s[t - off];
        __syncthreads();
        if (t >= off) s[t] += u;
        __syncthreads();
    }
    if (i < n) {
        int excl = s[t] - v + bsum_ex[blockIdx.x];
        offs[i] = excl;
        cntcur[i] = excl;                     // cursor for scatter
        dinv[i] = rsqrtf((float)v + 1.0f);    // deg includes self loop
        if (i == n - 1) offs[n] = E_;
    }
}

__global__ void scatter_csr(const int* __restrict__ ei, int* __restrict__ cur,
                            int* __restrict__ csr, int E_) {
    int e = blockIdx.x * BLK + threadIdx.x;
    if (e < E_) {
        int d = ei[E_ + e];
        int p = atomicAdd(&cur[d], 1);
        csr[p] = ei[e];  // src
    }
}

// ---------------- GEMM: hs = (x @ W) * dinv[row], H=16 ----------------
template <int F>
__global__ void gemm16(const float* __restrict__ x, const float* __restrict__ W,
                       const float* __restrict__ dinv, float* __restrict__ out, int n) {
    __shared__ float Ws[F * 16];
    __shared__ float xs[16 * F];
    int tid = threadIdx.x;
    for (int i = tid; i < F * 16; i += BLK) Ws[i] = W[i];
    int row0 = blockIdx.x * 16;
    for (int i = tid; i < 16 * F; i += BLK) {
        int r = i / F, c = i - r * F;
        int gr = row0 + r;
        xs[i] = (gr < n) ? x[(long long)gr * F + c] : 0.0f;
    }
    __syncthreads();
    int r = tid >> 4, c = tid & 15;
    float acc = 0.0f;
#pragma unroll 8
    for (int f = 0; f < F; ++f) acc += xs[r * F + f] * Ws[f * 16 + c];
    int gr = row0 + r;
    if (gr < n) out[gr * 16 + c] = acc * dinv[gr];
}

// ---------------- gather aggregation, H=16, fused init/skips ----------------
// out = bias[k] + (hs[i] + sum_{s in csr[i]} hs[s]) * dinv[i]  (+ relu(add1)+add1 + add2)
__global__ void gather16(const int* __restrict__ csr, const int* __restrict__ offs,
                         const float* __restrict__ dinv, const float* __restrict__ hs,
                         const float* __restrict__ bias, const float* __restrict__ add1,
                         const float* __restrict__ add2, float* __restrict__ out, int n) {
    int t = blockIdx.x * BLK + threadIdx.x;
    if (t >= n * 16) return;
    int i = t >> 4, k = t & 15;
    int beg = offs[i], end = offs[i + 1];
    float acc0 = 0.0f, acc1 = 0.0f;
    int j = beg;
    for (; j + 2 <= end; j += 2) {
        int s0 = csr[j], s1 = csr[j + 1];
        acc0 += hs[(s0 << 4) + k];
        acc1 += hs[(s1 << 4) + k];
    }
    if (j < end) { int s = csr[j]; acc0 += hs[(s << 4) + k]; }
    float v = bias[k] + (hs[t] + acc0 + acc1) * dinv[i];
    if (add1) { float a = add1[t]; v += fmaxf(a, 0.0f) + a; }
    if (add2) v += add2[t];
    out[t] = v;
}

// ---------------- gather aggregation, H=10 (final layer logits) ----------------
__global__ void gather10(const int* __restrict__ csr, const int* __restrict__ offs,
                         const float* __restrict__ dinv, const float* __restrict__ hs,
                         const float* __restrict__ bias, float* __restrict__ out, int n) {
    int t = blockIdx.x * BLK + threadIdx.x;
    if (t >= n * 10) return;
    int i = t / 10, k = t - i * 10;
    int beg = offs[i], end = offs[i + 1];
    float acc0 = 0.0f, acc1 = 0.0f;
    int j = beg;
    for (; j + 2 <= end; j += 2) {
        int s0 = csr[j], s1 = csr[j + 1];
        acc0 += hs[s0 * 10 + k];
        acc1 += hs[s1 * 10 + k];
    }
    if (j < end) { int s = csr[j]; acc0 += hs[s * 10 + k]; }
    out[t] = bias[k] + (hs[t] + acc0 + acc1) * dinv[i];
}

// ---------------- final GEMM: hs10 = (relu(h_f) @ We) * dinv[row] (16 -> 10) ----------------
__global__ void gemm_final(const float* __restrict__ hf, const float* __restrict__ We,
                           const float* __restrict__ dinv, float* __restrict__ out, int n) {
    __shared__ float Ws[160];
    if (threadIdx.x < 160) Ws[threadIdx.x] = We[threadIdx.x];
    __syncthreads();
    int t = blockIdx.x * BLK + threadIdx.x;
    if (t >= n * 10) return;
    int i = t / 10, j = t - i * 10;
    float acc = 0.0f;
#pragma unroll
    for (int k = 0; k < 16; ++k) acc += fmaxf(hf[i * 16 + k], 0.0f) * Ws[k * 10 + j];
    out[t] = acc * dinv[i];
}

// ---------------- log_softmax over 10 cols ----------------
__global__ void logsoftmax10(const float* __restrict__ logits, float* __restrict__ out, int n) {
    int i = blockIdx.x * BLK + threadIdx.x;
    if (i >= n) return;
    float v[10];
    float m = -INFINITY;
#pragma unroll
    for (int j = 0; j < 10; ++j) { v[j] = logits[i * 10 + j]; m = fmaxf(m, v[j]); }
    float s = 0.0f;
#pragma unroll
    for (int j = 0; j < 10; ++j) s += expf(v[j] - m);
    float ls = logf(s);
#pragma unroll
    for (int j = 0; j < 10; ++j) out[i * 10 + j] = v[j] - m - ls;
}

extern "C" void kernel_launch(void* const* d_in, const int* in_sizes, int n_in,
                              void* d_out, int out_size, void* d_ws, size_t ws_size,
                              hipStream_t stream) {
    const float* x_parent = (const float*)d_in[0];
    const float* x_child1 = (const float*)d_in[1];
    const float* x_child2 = (const float*)d_in[2];
    const float* x_fd     = (const float*)d_in[3];
    const int* e_p   = (const int*)d_in[4];
    const int* e_c1  = (const int*)d_in[5];
    const int* e_c2  = (const int*)d_in[6];
    const int* e_fd  = (const int*)d_in[7];
    const float* W1 = (const float*)d_in[8];
    const float* b1 = (const float*)d_in[9];
    const float* W2 = (const float*)d_in[10];
    const float* b2 = (const float*)d_in[11];
    const float* W3 = (const float*)d_in[12];
    const float* b3 = (const float*)d_in[13];
    const float* We = (const float*)d_in[14];
    const float* be = (const float*)d_in[15];

    const int n  = in_sizes[0] / 128;   // 100000
    const int E_ = in_sizes[4] / 2;     // 3200000

    // workspace layout (all 4B elems): floats then ints
    float* ws = (float*)d_ws;
    float* dinv = ws;                         // n (rebuilt per edge list)
    float* hs   = ws + (size_t)n;             // 16n (gemm out, premultiplied by dinv; reused as 10n)
    float* hp   = hs  + (size_t)16 * n;       // 16n
    float* hc1  = hp  + (size_t)16 * n;
    float* hc2  = hc1 + (size_t)16 * n;
    float* hf   = hc2 + (size_t)16 * n;
    float* logits = hf + (size_t)16 * n;      // 10n
    int* offs = (int*)(logits + (size_t)10 * n); // n+1
    int* cur  = offs + (size_t)n + 1;            // n (hist counts -> cursor)
    int* bsum = cur + (size_t)n;                 // 512
    int* csr  = bsum + 512;                      // E

    const int gN   = (n + BLK - 1) / BLK;        // 391
    const int gN16 = (n * 16 + BLK - 1) / BLK;
    const int gN10 = (n * 10 + BLK - 1) / BLK;
    const int gE   = (E_ + BLK - 1) / BLK;
    const int gRow = (n + 15) / 16;

    // build dst-CSR (+ dinv) for one edge list into shared offs/csr buffers
    auto build_csr = [&](const int* ei) {
        zero_int<<<gN, BLK, 0, stream>>>(cur, n);
        hist_dst<<<gE, BLK, 0, stream>>>(ei + E_, cur, E_);
        scan_block<<<gN, BLK, 0, stream>>>(cur, bsum, n);
        scan_bsums<<<1, 512, 0, stream>>>(bsum, gN);
        scan_final<<<gN, BLK, 0, stream>>>(cur, bsum, offs, dinv, n, E_);
        scatter_csr<<<gE, BLK, 0, stream>>>(ei, cur, csr, E_);
    };

    // L1: h_parent = conv(x_parent, e_p, W1, b1)
    build_csr(e_p);
    gemm16<128><<<gRow, BLK, 0, stream>>>(x_parent, W1, dinv, hs, n);
    gather16<<<gN16, BLK, 0, stream>>>(csr, offs, dinv, hs, b1, nullptr, nullptr, hp, n);

    // L2: h_c1 = conv(x_child1, e_c1, W2, b2) + relu(hp) + hp
    build_csr(e_c1);
    gemm16<129><<<gRow, BLK, 0, stream>>>(x_child1, W2, dinv, hs, n);
    gather16<<<gN16, BLK, 0, stream>>>(csr, offs, dinv, hs, b2, hp, nullptr, hc1, n);

    // L3: h_c2 = conv(x_child2, e_c2, W3, b3) + relu(hc1) + hc1
    build_csr(e_c2);
    gemm16<130><<<gRow, BLK, 0, stream>>>(x_child2, W3, dinv, hs, n);
    gather16<<<gN16, BLK, 0, stream>>>(csr, offs, dinv, hs, b3, hc1, nullptr, hc2, n);

    // L4: h_f = conv(x_fd, e_fd, W2, b2) + relu(hc2) + hc1 + hc2
    build_csr(e_fd);
    gemm16<129><<<gRow, BLK, 0, stream>>>(x_fd, W2, dinv, hs, n);
    gather16<<<gN16, BLK, 0, stream>>>(csr, offs, dinv, hs, b2, hc2, hc1, hf, n);

    // L5: out = conv(relu(h_f), e_fd, We, be) -> log_softmax   (reuses e_fd CSR + dinv)
    gemm_final<<<gN10, BLK, 0, stream>>>(hf, We, dinv, hs, n);  // hs reused as [n,10]
    gather10<<<gN10, BLK, 0, stream>>>(csr, offs, dinv, hs, be, logits, n);
    logsoftmax10<<<gN10, BLK, 0, stream>>>(logits, (float*)d_out, n);
}